// Round 9
// baseline (304.587 us; speedup 1.0000x reference)
//
#include <hip/hip_runtime.h>

#define NN 25600      // nodes = 160*160
#define HH 160
#define WW 160
#define C2 256

// ---- bf16 weight pack offsets (ushorts) ----
#define B_WIN   0
#define B_WID   32768
#define B_WGAT  65536      // 2 layers x 65536
#define B_WOUT  196608
#define B_WEND  262144

// ---- small fp32 param offsets inside cvt (floats) ----
#define C_BNA   0          // 2x256 BN scale
#define C_BNB   512        // 2x256 BN shift (bias/mean folded)
#define C_ASRC  1024       // 2x256
#define C_ADST  1536       // 2x256
#define C_SEW1  2048       // 64x256
#define C_SEB1  18432      // 64
#define C_SEW2  18496      // 256x64
#define C_SEB2  34880      // 256
#define C_END   35136

typedef __attribute__((ext_vector_type(8))) short bfrag;   // 8 bf16 (4 VGPRs)
typedef __attribute__((ext_vector_type(4))) float ffrag;   // 4 fp32 acc

__device__ __forceinline__ float b2f(unsigned short u) {
    union { unsigned int ui; float f; } v; v.ui = ((unsigned int)u) << 16; return v.f;
}
__device__ __forceinline__ unsigned short f2b(float f) {
    union { float f; unsigned int u; } v; v.f = f;
    unsigned int u = v.u;
    unsigned int r = (u + 0x7FFFu + ((u >> 16) & 1u)) >> 16;
    return (unsigned short)r;
}
__device__ __forceinline__ float lo16f(unsigned int w) {
    union { unsigned int ui; float f; } v; v.ui = w << 16; return v.f;
}
__device__ __forceinline__ float hi16f(unsigned int w) {
    union { unsigned int ui; float f; } v; v.ui = w & 0xFFFF0000u; return v.f;
}
// Wave-uniform dtype probe on first 512 halfwords of x.
__device__ __forceinline__ bool probe_f32(const unsigned short* __restrict__ x) {
    int l = threadIdx.x & 63;
    bool wild = false;
#pragma unroll
    for (int i = 0; i < 8; ++i) {
        float v = b2f(x[l * 8 + i]);
        wild |= !(fabsf(v) < 1e6f);
    }
    return __any(wild);
}
__device__ __forceinline__ float ldf(const void* p, long i, bool f32) {
    return f32 ? ((const float*)p)[i] : b2f(((const unsigned short*)p)[i]);
}

// ---------------------------------------------------------------------------
// prep: pack weights bf16, fold BN, convert small params, zero means,
// transpose x -> bf16 [25600][128]. Grid = 400.
// ---------------------------------------------------------------------------
__global__ __launch_bounds__(256) void prep_kernel(
    const unsigned short* __restrict__ xp,
    const void* pwin, const void* pwid, const void* pwgat, const void* pwout,
    const void* pasrc, const void* padst, const void* pgbias,
    const void* pbng, const void* pbnb, const void* pbnm, const void* pbnv,
    const void* psew1, const void* pseb1, const void* psew2, const void* pseb2,
    unsigned short* __restrict__ wb, float* __restrict__ cvt,
    float* __restrict__ means, unsigned short* __restrict__ xT)
{
    __shared__ unsigned short T[64 * 136];
    const bool f32 = probe_f32(xp);
    const int tid = threadIdx.x;
    const int bid = blockIdx.x;
    const int gid = bid * 256 + tid;
    const int stride = gridDim.x * 256;

    if (bid == 0) means[tid] = 0.f;

    for (int i = gid; i < B_WEND; i += stride) {
        const void* s; int o;
        if      (i < B_WID)   { s = pwin;  o = i - B_WIN; }
        else if (i < B_WGAT)  { s = pwid;  o = i - B_WID; }
        else if (i < B_WOUT)  { s = pwgat; o = i - B_WGAT; }
        else                  { s = pwout; o = i - B_WOUT; }
        wb[i] = f32 ? f2b(((const float*)s)[o]) : ((const unsigned short*)s)[o];
    }
    for (int i = gid; i < 512; i += stride) {
        float sc = ldf(pbng, i, f32) * rsqrtf(ldf(pbnv, i, f32) + 1e-5f);
        cvt[C_BNA + i] = sc;
        cvt[C_BNB + i] = (ldf(pgbias, i, f32) - ldf(pbnm, i, f32)) * sc + ldf(pbnb, i, f32);
        cvt[C_ASRC + i] = ldf(pasrc, i, f32);
        cvt[C_ADST + i] = ldf(padst, i, f32);
    }
    for (int i = gid; i < 16384; i += stride) {
        cvt[C_SEW1 + i] = ldf(psew1, i, f32);
        cvt[C_SEW2 + i] = ldf(psew2, i, f32);
    }
    for (int i = gid; i < 64; i += stride)  cvt[C_SEB1 + i] = ldf(pseb1, i, f32);
    for (int i = gid; i < 256; i += stride) cvt[C_SEB2 + i] = ldf(pseb2, i, f32);

    {
        const int n0 = bid * 64;
        const int nl = tid & 63;
#pragma unroll
        for (int i = 0; i < 32; ++i) {
            int c = i * 4 + (tid >> 6);
            long idx = (long)c * NN + n0 + nl;
            T[nl * 136 + c] = f32 ? f2b(((const float*)xp)[idx]) : xp[idx];
        }
        __syncthreads();
#pragma unroll
        for (int i = 0; i < 4; ++i) {
            int n = tid >> 2, c0 = (tid & 3) * 32 + i * 8;
            uint4 v = *(const uint4*)&T[n * 136 + c0];
            *(uint4*)(xT + (long)(n0 + n) * 128 + c0) = v;
        }
    }
}

// ---------------------------------------------------------------------------
// MFMA GEMM (dual-B, K=128): xf0=A@Wi^T, idb=A@Wd^T. Tile 128x64, grid 200x4.
// ---------------------------------------------------------------------------
struct SmemG2 { unsigned short As[128*40], Bi[64*40], Bd[64*40]; };
struct SmemC2 { unsigned short Cs[128*72]; };
union  SmemX2 { SmemG2 s; SmemC2 c; };

__global__ __launch_bounds__(256) void mfma_gemm_x2_kernel(
    const unsigned short* __restrict__ A16,
    const unsigned short* __restrict__ Wi16,
    const unsigned short* __restrict__ Wd16,
    unsigned short* __restrict__ xf16,
    unsigned short* __restrict__ idb16)
{
    __shared__ SmemX2 sm;
    const int tid = threadIdx.x;
    const int m0 = blockIdx.x * 128, o0 = blockIdx.y * 64;
    const int lane = tid & 63, wv = tid >> 6;
    const int wm = wv >> 1, wn = wv & 1;
    const int lr = lane & 15, quad = lane >> 4;

    ffrag ai[4][2], ad[4][2];
#pragma unroll
    for (int mt = 0; mt < 4; ++mt)
#pragma unroll
        for (int nt = 0; nt < 2; ++nt) { ai[mt][nt] = (ffrag){0,0,0,0}; ad[mt][nt] = (ffrag){0,0,0,0}; }

    for (int k0 = 0; k0 < 128; k0 += 32) {
#pragma unroll
        for (int c = tid; c < 512; c += 256) {
            int row = c >> 2, q = c & 3;
            *(uint4*)&sm.s.As[row * 40 + q * 8] =
                *(const uint4*)(A16 + (long)(m0 + row) * 128 + k0 + q * 8);
        }
        {
            int row = tid >> 2, q = tid & 3;
            *(uint4*)&sm.s.Bi[row * 40 + q * 8] =
                *(const uint4*)(Wi16 + (long)(o0 + row) * 128 + k0 + q * 8);
            *(uint4*)&sm.s.Bd[row * 40 + q * 8] =
                *(const uint4*)(Wd16 + (long)(o0 + row) * 128 + k0 + q * 8);
        }
        __syncthreads();
        bfrag a[4], bi[2], bd[2];
#pragma unroll
        for (int mt = 0; mt < 4; ++mt)
            a[mt] = *(const bfrag*)&sm.s.As[(wm * 64 + mt * 16 + lr) * 40 + quad * 8];
#pragma unroll
        for (int nt = 0; nt < 2; ++nt) {
            bi[nt] = *(const bfrag*)&sm.s.Bi[(wn * 32 + nt * 16 + lr) * 40 + quad * 8];
            bd[nt] = *(const bfrag*)&sm.s.Bd[(wn * 32 + nt * 16 + lr) * 40 + quad * 8];
        }
#pragma unroll
        for (int mt = 0; mt < 4; ++mt)
#pragma unroll
            for (int nt = 0; nt < 2; ++nt) {
                ai[mt][nt] = __builtin_amdgcn_mfma_f32_16x16x32_bf16(a[mt], bi[nt], ai[mt][nt], 0, 0, 0);
                ad[mt][nt] = __builtin_amdgcn_mfma_f32_16x16x32_bf16(a[mt], bd[nt], ad[mt][nt], 0, 0, 0);
            }
        __syncthreads();
    }
#pragma unroll
    for (int mt = 0; mt < 4; ++mt)
#pragma unroll
        for (int nt = 0; nt < 2; ++nt)
#pragma unroll
            for (int r = 0; r < 4; ++r)
                sm.c.Cs[(wm * 64 + mt * 16 + quad * 4 + r) * 72 + wn * 32 + nt * 16 + lr] = f2b(ai[mt][nt][r]);
    __syncthreads();
#pragma unroll
    for (int it = 0; it < 4; ++it) {
        int e = it * 256 + tid;
        int row = e >> 3, c8 = (e & 7) * 8;
        *(uint4*)(xf16 + (long)(m0 + row) * C2 + o0 + c8) = *(const uint4*)&sm.c.Cs[row * 72 + c8];
    }
    __syncthreads();
#pragma unroll
    for (int mt = 0; mt < 4; ++mt)
#pragma unroll
        for (int nt = 0; nt < 2; ++nt)
#pragma unroll
            for (int r = 0; r < 4; ++r)
                sm.c.Cs[(wm * 64 + mt * 16 + quad * 4 + r) * 72 + wn * 32 + nt * 16 + lr] = f2b(ad[mt][nt][r]);
    __syncthreads();
#pragma unroll
    for (int it = 0; it < 4; ++it) {
        int e = it * 256 + tid;
        int row = e >> 3, c8 = (e & 7) * 8;
        *(uint4*)(idb16 + (long)(m0 + row) * C2 + o0 + c8) = *(const uint4*)&sm.c.Cs[row * 72 + c8];
    }
}

// ---------------------------------------------------------------------------
// gemm_hop: C = A @ W^T, 128x128 tile (grid 200x2), K=256, BK=32.
// aggA=0: A read from Ap. aggA=1: A built on the fly per K-slice (head=k0/32):
//   A[m][c] = relu(bn(sum_k alpha[m,k]*h[nbr_k][c])) + xf_old[m][c]
//   (side-writes xf_new when xfout && blockIdx.y==0)
// epi=1: attention coeffs from fp32 accumulators -> al_s/al_d.
// epi=2: column sums -> means atomics.
// ---------------------------------------------------------------------------
__global__ __launch_bounds__(256) void gemm_hop_kernel(
    const unsigned short* __restrict__ Ap,
    const unsigned short* __restrict__ hsrc,
    const float* __restrict__ alsA, const float* __restrict__ aldA,
    const unsigned short* __restrict__ xfold,
    unsigned short* __restrict__ xfout,
    const float* __restrict__ bnA, const float* __restrict__ bnB,
    const unsigned short* __restrict__ W16,
    unsigned short* __restrict__ C16,
    const float* __restrict__ asrc, const float* __restrict__ adst,
    float* __restrict__ al_sO, float* __restrict__ al_dO,
    float* __restrict__ means,
    int aggA, int epi)
{
    __shared__ union {
        struct { unsigned short As[128*40], Bs[128*40]; float alpha[128][11]; } s;
        unsigned short Cs[128*136];
    } sm;
    const int SI[11] = { 1, 1, 1, 0, 0, -1, -1, -1, -2,  0, 0};
    const int SJ[11] = { 1, 0,-1, 1,-1,  1,  0, -1,  0, -2, 0};
    const int tid = threadIdx.x;
    const int m0 = blockIdx.x * 128, o0 = blockIdx.y * 128;
    const int lane = tid & 63, wv = tid >> 6;
    const int wm = wv >> 1, wn = wv & 1;
    const int lr = lane & 15, quad = lane >> 4;

    ffrag acc[4][4];
#pragma unroll
    for (int mt = 0; mt < 4; ++mt)
#pragma unroll
        for (int nt = 0; nt < 4; ++nt) acc[mt][nt] = (ffrag){0,0,0,0};

    for (int k0 = 0; k0 < 256; k0 += 32) {
        // stage B (128 rows x 32 ch)
#pragma unroll
        for (int c = tid; c < 512; c += 256) {
            int row = c >> 2, q = c & 3;
            *(uint4*)&sm.s.Bs[row * 40 + q * 8] =
                *(const uint4*)(W16 + (long)(o0 + row) * 256 + k0 + q * 8);
        }
        if (aggA) {
            if (tid < 128) {     // softmax alphas for this K-slice's head
                const int head = k0 >> 5;
                const int m = m0 + tid;
                const int i2 = m / WW, j2 = m - i2 * WW;
                const float ald = aldA[m * 8 + head];
                float e[11]; float mx = -1e30f;
#pragma unroll
                for (int k = 0; k < 11; ++k) {
                    int si = i2 + SI[k], sj = j2 + SJ[k];
                    bool ok = (si >= 0) & (si < HH) & (sj >= 0) & (sj < WW);
                    float v = ok ? alsA[(si * WW + sj) * 8 + head] + ald : -1e30f;
                    v = v > 0.f ? v : 0.2f * v;
                    e[k] = v; mx = fmaxf(mx, v);
                }
                float den = 0.f;
#pragma unroll
                for (int k = 0; k < 11; ++k) { float p = __expf(e[k] - mx); e[k] = p; den += p; }
                const float inv = 1.f / (den + 1e-16f);
#pragma unroll
                for (int k = 0; k < 11; ++k) sm.s.alpha[tid][k] = e[k] * inv;
            }
        } else {
#pragma unroll
            for (int c = tid; c < 512; c += 256) {
                int row = c >> 2, q = c & 3;
                *(uint4*)&sm.s.As[row * 40 + q * 8] =
                    *(const uint4*)(Ap + (long)(m0 + row) * 256 + k0 + q * 8);
            }
        }
        __syncthreads();
        if (aggA) {
            // build A-tile: thread = (row ml, 16-ch half)
            const int ml = tid >> 1, half = tid & 1;
            const int m = m0 + ml;
            const int i2 = m / WW, j2 = m - i2 * WW;
            const int cb = k0 + half * 16;
            float a16[16];
#pragma unroll
            for (int q = 0; q < 16; ++q) a16[q] = 0.f;
#pragma unroll
            for (int k = 0; k < 11; ++k) {
                float al = sm.s.alpha[ml][k];
                int si = i2 + SI[k], sj = j2 + SJ[k];
                bool ok = (si >= 0) & (si < HH) & (sj >= 0) & (sj < WW);
                long srcn = ok ? (long)(si * WW + sj) : (long)m;
                uint4 v0 = *(const uint4*)(hsrc + srcn * C2 + cb);
                uint4 v1 = *(const uint4*)(hsrc + srcn * C2 + cb + 8);
                a16[0]  += al * lo16f(v0.x); a16[1]  += al * hi16f(v0.x);
                a16[2]  += al * lo16f(v0.y); a16[3]  += al * hi16f(v0.y);
                a16[4]  += al * lo16f(v0.z); a16[5]  += al * hi16f(v0.z);
                a16[6]  += al * lo16f(v0.w); a16[7]  += al * hi16f(v0.w);
                a16[8]  += al * lo16f(v1.x); a16[9]  += al * hi16f(v1.x);
                a16[10] += al * lo16f(v1.y); a16[11] += al * hi16f(v1.y);
                a16[12] += al * lo16f(v1.z); a16[13] += al * hi16f(v1.z);
                a16[14] += al * lo16f(v1.w); a16[15] += al * hi16f(v1.w);
            }
            uint4 r0 = *(const uint4*)(xfold + (long)m * C2 + cb);
            uint4 r1 = *(const uint4*)(xfold + (long)m * C2 + cb + 8);
            float res[16] = {lo16f(r0.x),hi16f(r0.x),lo16f(r0.y),hi16f(r0.y),
                             lo16f(r0.z),hi16f(r0.z),lo16f(r0.w),hi16f(r0.w),
                             lo16f(r1.x),hi16f(r1.x),lo16f(r1.y),hi16f(r1.y),
                             lo16f(r1.z),hi16f(r1.z),lo16f(r1.w),hi16f(r1.w)};
            unsigned int w[8];
#pragma unroll
            for (int q = 0; q < 8; ++q) {
                int c0i = cb + q * 2;
                float g0 = a16[q*2]   * bnA[c0i]     + bnB[c0i];
                float g1 = a16[q*2+1] * bnA[c0i + 1] + bnB[c0i + 1];
                g0 = fmaxf(g0, 0.f) + res[q*2];
                g1 = fmaxf(g1, 0.f) + res[q*2+1];
                w[q] = (unsigned int)f2b(g0) | ((unsigned int)f2b(g1) << 16);
            }
            uint4 p0 = make_uint4(w[0], w[1], w[2], w[3]);
            uint4 p1 = make_uint4(w[4], w[5], w[6], w[7]);
            *(uint4*)&sm.s.As[ml * 40 + half * 16]     = p0;
            *(uint4*)&sm.s.As[ml * 40 + half * 16 + 8] = p1;
            if (xfout != nullptr && blockIdx.y == 0) {
                *(uint4*)(xfout + (long)m * C2 + cb)     = p0;
                *(uint4*)(xfout + (long)m * C2 + cb + 8) = p1;
            }
            __syncthreads();
        }
        // MFMA
        bfrag a[4], b[4];
#pragma unroll
        for (int mt = 0; mt < 4; ++mt)
            a[mt] = *(const bfrag*)&sm.s.As[(wm * 64 + mt * 16 + lr) * 40 + quad * 8];
#pragma unroll
        for (int nt = 0; nt < 4; ++nt)
            b[nt] = *(const bfrag*)&sm.s.Bs[(wn * 64 + nt * 16 + lr) * 40 + quad * 8];
#pragma unroll
        for (int mt = 0; mt < 4; ++mt)
#pragma unroll
            for (int nt = 0; nt < 4; ++nt)
                acc[mt][nt] = __builtin_amdgcn_mfma_f32_16x16x32_bf16(a[mt], b[nt], acc[mt][nt], 0, 0, 0);
        __syncthreads();
    }

    // C store via LDS (coalesced uint4)
#pragma unroll
    for (int mt = 0; mt < 4; ++mt)
#pragma unroll
        for (int nt = 0; nt < 4; ++nt)
#pragma unroll
            for (int r = 0; r < 4; ++r)
                sm.Cs[(wm * 64 + mt * 16 + quad * 4 + r) * 136 + wn * 64 + nt * 16 + lr] = f2b(acc[mt][nt][r]);
    __syncthreads();
#pragma unroll
    for (int it = 0; it < 8; ++it) {
        int e = it * 256 + tid;
        int row = e >> 4, c8 = (e & 15) * 8;
        *(uint4*)(C16 + (long)(m0 + row) * C2 + o0 + c8) = *(const uint4*)&sm.Cs[row * 136 + c8];
    }

    if (epi == 1) {
#pragma unroll
        for (int h2 = 0; h2 < 2; ++h2) {
            const int gh = (o0 >> 5) + wn * 2 + h2;
            const float as0 = asrc[gh * 32 + lr], as1 = asrc[gh * 32 + 16 + lr];
            const float ad0 = adst[gh * 32 + lr], ad1 = adst[gh * 32 + 16 + lr];
#pragma unroll
            for (int mt = 0; mt < 4; ++mt)
#pragma unroll
                for (int r = 0; r < 4; ++r) {
                    float ps = acc[mt][h2*2][r] * as0 + acc[mt][h2*2+1][r] * as1;
                    float pd = acc[mt][h2*2][r] * ad0 + acc[mt][h2*2+1][r] * ad1;
#pragma unroll
                    for (int sh = 1; sh < 16; sh <<= 1) {
                        ps += __shfl_xor(ps, sh);
                        pd += __shfl_xor(pd, sh);
                    }
                    if (lr == 0) {
                        int m = m0 + wm * 64 + mt * 16 + quad * 4 + r;
                        al_sO[m * 8 + gh] = ps;
                        al_dO[m * 8 + gh] = pd;
                    }
                }
        }
    } else if (epi == 2) {
#pragma unroll
        for (int nt = 0; nt < 4; ++nt) {
            float p = 0.f;
#pragma unroll
            for (int mt = 0; mt < 4; ++mt)
#pragma unroll
                for (int r = 0; r < 4; ++r) p += acc[mt][nt][r];
            p += __shfl_xor(p, 16);
            p += __shfl_xor(p, 32);
            if (quad == 0) atomicAdd(&means[o0 + wn * 64 + nt * 16 + lr], p);
        }
    }
}

// ---------------------------------------------------------------------------
// Final: SE vector from means (redundant per block), then
// out[c][n] = y[n][c]*s[c] + id[n][c] (transposed store; dtype by probe).
// ---------------------------------------------------------------------------
__global__ __launch_bounds__(256) void final_kernel(
    const unsigned short* __restrict__ x_probe,
    const unsigned short* __restrict__ y16,
    const unsigned short* __restrict__ idb16,
    const float* __restrict__ means,
    const float* __restrict__ cvt,
    void* __restrict__ outp)
{
    __shared__ float T[64][65];
    __shared__ float mv[256];
    __shared__ float hv[64];
    __shared__ float sv[64];
    const bool f32o = probe_f32(x_probe);
    const int t = threadIdx.x;
    const int n0 = blockIdx.x * 64, c0 = blockIdx.y * 64;

    mv[t] = means[t] * (1.0f / 25600.0f);
    __syncthreads();
    if (t < 64) {
        const float* w1 = cvt + C_SEW1 + t * 256;
        float s = cvt[C_SEB1 + t];
        for (int cc = 0; cc < 256; cc += 4) {
            float4 wv = *(const float4*)(w1 + cc);
            s += wv.x * mv[cc] + wv.y * mv[cc+1] + wv.z * mv[cc+2] + wv.w * mv[cc+3];
        }
        hv[t] = fmaxf(s, 0.f);
    }
    __syncthreads();
    if (t < 64) {
        const int c = c0 + t;
        const float* w2 = cvt + C_SEW2 + c * 64;
        float s = cvt[C_SEB2 + c];
        for (int k = 0; k < 64; k += 4) {
            float4 wv = *(const float4*)(w2 + k);
            s += wv.x * hv[k] + wv.y * hv[k+1] + wv.z * hv[k+2] + wv.w * hv[k+3];
        }
        sv[t] = 1.0f / (1.0f + __expf(-s));
    }
    __syncthreads();
#pragma unroll
    for (int it = 0; it < 16; ++it) {
        int e = t + it * 256;
        int nn = e >> 6, cc = e & 63;
        long idx = (long)(n0 + nn) * C2 + c0 + cc;
        T[cc][nn] = b2f(y16[idx]) * sv[cc] + b2f(idb16[idx]);
    }
    __syncthreads();
#pragma unroll
    for (int it = 0; it < 16; ++it) {
        int e = t + it * 256;
        int cc = e >> 6, nn = e & 63;
        long idx = (long)(c0 + cc) * NN + n0 + nn;
        float v = T[cc][nn];
        if (f32o) ((float*)outp)[idx] = v;
        else      ((unsigned short*)outp)[idx] = f2b(v);
    }
}

extern "C" void kernel_launch(void* const* d_in, const int* in_sizes, int n_in,
                              void* d_out, int out_size, void* d_ws, size_t ws_size,
                              hipStream_t stream) {
    float* ws = (float*)d_ws;
    float* cvt   = ws;                          // C_END small fp32 params
    float* means = ws + 35200;                  // 256 (64-aligned)
    float* als1  = means + 256;                 // 204800 each
    float* ald1  = als1 + 204800;
    float* als2  = ald1 + 204800;
    float* ald2  = als2 + 204800;
    unsigned short* wb16  = (unsigned short*)(ald2 + 204800);  // 262144
    unsigned short* xT16  = wb16 + B_WEND;                     // 25600*128
    unsigned short* xf0   = xT16 + NN * 128;                   // 25600*256
    unsigned short* xf1   = xf0 + NN * 256;                    // 25600*256
    unsigned short* hA    = xf1 + NN * 256;                    // 25600*256 (h1, then y)
    unsigned short* hB    = hA + NN * 256;                     // 25600*256 (h2)
    unsigned short* idb16 = hB + NN * 256;                     // 25600*256

    const unsigned short* xp = (const unsigned short*)d_in[0];

    dim3 b256(256);
    dim3 gx2(NN / 128, 4);             // 200 x 4 (128x64 tiles)
    dim3 ghop(NN / 128, 2);            // 200 x 2 (128x128 tiles)
    dim3 gfin(NN / 64, C2 / 64);       // 400 x 4

    prep_kernel<<<400, b256, 0, stream>>>(
        xp, d_in[2], d_in[1], d_in[3], d_in[11],
        d_in[4], d_in[5], d_in[6], d_in[7], d_in[8], d_in[9], d_in[10],
        d_in[12], d_in[13], d_in[14], d_in[15],
        wb16, cvt, means, xT16);

    mfma_gemm_x2_kernel<<<gx2, b256, 0, stream>>>(
        xT16, wb16 + B_WIN, wb16 + B_WID, xf0, idb16);

    // hop 1 GEMM: h1 = xf0 @ W1^T, attn epilogue -> als1/ald1
    gemm_hop_kernel<<<ghop, b256, 0, stream>>>(
        xf0, nullptr, nullptr, nullptr, nullptr, nullptr,
        nullptr, nullptr,
        wb16 + B_WGAT, hA,
        cvt + C_ASRC, cvt + C_ADST, als1, ald1, nullptr,
        0, 1);

    // hop 2 GEMM: A = agg(h1, als1, xf0) (writes xf1), h2 = A @ W2^T, attn -> als2/ald2
    gemm_hop_kernel<<<ghop, b256, 0, stream>>>(
        nullptr, hA, als1, ald1, xf0, xf1,
        cvt + C_BNA, cvt + C_BNB,
        wb16 + B_WGAT + 65536, hB,
        cvt + C_ASRC + 256, cvt + C_ADST + 256, als2, ald2, nullptr,
        1, 1);

    // out GEMM: A = agg(h2, als2, xf1) (not stored), y = A @ Wout^T, colsum -> means
    gemm_hop_kernel<<<ghop, b256, 0, stream>>>(
        nullptr, hB, als2, ald2, xf1, nullptr,
        cvt + C_BNA + 256, cvt + C_BNB + 256,
        wb16 + B_WOUT, hA,
        nullptr, nullptr, nullptr, nullptr, means,
        1, 2);

    final_kernel<<<gfin, b256, 0, stream>>>(xp, hA, idb16, means, cvt, d_out);
}